// Round 16
// baseline (1007.316 us; speedup 1.0000x reference)
//
#include <hip/hip_runtime.h>
#include <math.h>

typedef unsigned short u16;
typedef unsigned int u32;
typedef _Float16 f16;
typedef f16 f16x8 __attribute__((ext_vector_type(8)));
typedef float f32x4 __attribute__((ext_vector_type(4)));

#define DIM 512
#define D_IN 4096
#define N_OBJS 2048
#define N_RELS 32768
#define N_OBJ_CLS 151
#define N_REL_CLS 51
#define EPSV 1e-5f
#define GOUT 2048          // packed GRU gate row width: [rz 1024 | in 512 | hn 512]

// d_out layout (floats)
#define OFF_HOBJ  0
#define OFF_HEDGE (N_OBJS*DIM)
#define OFF_OLOG  (OFF_HEDGE + N_RELS*DIM)
#define OFF_PLOG  (OFF_OLOG + N_OBJS*N_OBJ_CLS)
#define OFF_LBL   (OFF_PLOG + N_RELS*N_REL_CLS)
#define OFF_RI    (OFF_LBL + N_OBJS)

__device__ __forceinline__ float sigmoidf_(float x) { return 1.0f / (1.0f + expf(-x)); }
__device__ __forceinline__ u16 f2h_(float f) {
    union { f16 h; u16 u; } c; c.h = (f16)f; return c.u;
}
__device__ __forceinline__ float h2f_(u16 u) {
    union { f16 h; u16 u; } c; c.u = u; return (float)c.h;
}

// 8 fp32 -> packed f16 (uint4)
__device__ __forceinline__ void cvt8h1(const float* f, uint4& h) {
    u32 hh[8];
#pragma unroll
    for (int i = 0; i < 8; i++) hh[i] = f2h_(f[i]);
    h.x = hh[0] | (hh[1] << 16); h.y = hh[2] | (hh[3] << 16);
    h.z = hh[4] | (hh[5] << 16); h.w = hh[6] | (hh[7] << 16);
}
// 8 fp32 -> hi + lo (a ~= hi + lo)
__device__ __forceinline__ void cvt8h2(const float* f, uint4& h, uint4& l) {
    u32 hh[8], ll[8];
#pragma unroll
    for (int i = 0; i < 8; i++) {
        u16 x = f2h_(f[i]);
        hh[i] = x;
        ll[i] = f2h_(f[i] - h2f_(x));
    }
    h.x = hh[0] | (hh[1] << 16); h.y = hh[2] | (hh[3] << 16);
    h.z = hh[4] | (hh[5] << 16); h.w = hh[6] | (hh[7] << 16);
    l.x = ll[0] | (ll[1] << 16); l.y = ll[2] | (ll[3] << 16);
    l.z = ll[4] | (ll[5] << 16); l.w = ll[6] | (ll[7] << 16);
}

// LDS offset (u16 units) for (row, chunk8) in a [rows][32] tile, XOR-swizzled
__device__ __forceinline__ int swzo(int row, int c) {
    return row * 32 + ((c ^ ((row >> 1) & 3)) << 3);
}

// XCD-chunked bijective blockIdx swizzle (requires nwg % 8 == 0)
__device__ __forceinline__ int xcdswz(int orig, int nwg) {
    const int q = nwg >> 3;
    return (orig & 7) * q + (orig >> 3);
}

// async global->LDS, 16B per lane; LDS dest = wave-uniform base + lane*16
__device__ __forceinline__ void gload16(const void* g, void* l) {
    __builtin_amdgcn_global_load_lds(
        (const __attribute__((address_space(1))) void*)g,
        (__attribute__((address_space(3))) void*)l, 16, 0, 0);
}

// ---------------------------------------------------------------------------
// fp32 -> f16 (weights)
__global__ __launch_bounds__(256) void convert_h(const float* __restrict__ src,
    u16* __restrict__ hi, int n4)
{
    const int i = blockIdx.x * 256 + threadIdx.x;
    if (i >= n4) return;
    const float4 v = ((const float4*)src)[i];
    ((ushort4*)hi)[i] = make_ushort4(f2h_(v.x), f2h_(v.y), f2h_(v.z), f2h_(v.w));
}

// pack Wrz[1024][1024]: k<512 from Wih(f16), else Whh(f16) (r,z row panels)
__global__ __launch_bounds__(256) void pack_rz(const u16* __restrict__ ih,
    const u16* __restrict__ hh, u16* __restrict__ wrz)
{
    const int idx = blockIdx.x * 256 + threadIdx.x;   // 1024*128 uint4s
    const int n = idx >> 7, kk = (idx & 127) * 8;
    const uint4 v = (kk < 512) ? *(const uint4*)&ih[(size_t)n * 512 + kk]
                               : *(const uint4*)&hh[(size_t)n * 512 + kk - 512];
    *(uint4*)&wrz[(size_t)n * 1024 + kk] = v;
}

// brz[j] = bih[j] + bhh[j], j < 1024
__global__ __launch_bounds__(256) void pack_brz(const float* __restrict__ bih,
    const float* __restrict__ bhh, float* __restrict__ brz)
{
    const int j = blockIdx.x * 256 + threadIdx.x;
    brz[j] = bih[j] + bhh[j];
}

// ---------------------------------------------------------------------------
// BODY: f16 GEMM, fp32 A split on the fly (AT terms), 1-deep A-reg prefetch,
// B f16 via global_load_lds. Caller provides LDS. BK=32, N = NX*128 exact.
// ---------------------------------------------------------------------------
template<bool RELU, int AT, bool WSPLIT>
__device__ __forceinline__ void gemm_a32_body(
    int id, u16* sAh, u16* sBh, u16* sAl,
    const float* __restrict__ A, const u16* __restrict__ Bhi,
    const float* __restrict__ bias, u16* __restrict__ Chi, u16* __restrict__ Clo,
    int NX, int K)
{
    const int m0 = (id / NX) * 128, n0 = (id % NX) * 128;
    const int N = NX * 128;
    const int t = threadIdx.x;
    const int wid = t >> 6, lane = t & 63;
    const int wm = (wid >> 1) * 64, wn = (wid & 1) * 64;
    const int lr = lane & 15, lk = lane >> 4;

    f32x4 acc[4][4] = {};

    const int sr = t >> 1;
    const int sc = (t & 1) * 2;
    const float* Ap = A + (size_t)(m0 + sr) * K + (t & 1) * 16;

    const int rB = (wid * 2) * 16 + (lane >> 2);
    const int cB = (lane & 3) ^ ((rB >> 1) & 3);
    const u16* Bp0 = Bhi + (size_t)(n0 + rB) * K + cB * 8;
    const u16* Bp1 = Bp0 + (size_t)16 * K;
    u16* Bd0 = &sBh[(wid * 2) * 512];
    u16* Bd1 = Bd0 + 512;

    float fv[16];
    *(float4*)&fv[0]  = *(const float4*)(Ap);
    *(float4*)&fv[4]  = *(const float4*)(Ap + 4);
    *(float4*)&fv[8]  = *(const float4*)(Ap + 8);
    *(float4*)&fv[12] = *(const float4*)(Ap + 12);

    for (int k0 = 0; k0 < K; k0 += 32) {
        uint4 ah0, ah1, al0, al1;
        if (AT == 2) { cvt8h2(fv, ah0, al0); cvt8h2(fv + 8, ah1, al1); }
        else         { cvt8h1(fv, ah0);      cvt8h1(fv + 8, ah1); }

        __syncthreads();                       // previous LDS reads complete
        gload16(Bp0 + k0, Bd0);
        gload16(Bp1 + k0, Bd1);
        *(uint4*)&sAh[swzo(sr, sc)]     = ah0;
        *(uint4*)&sAh[swzo(sr, sc + 1)] = ah1;
        if (AT == 2) {
            *(uint4*)&sAl[swzo(sr, sc)]     = al0;
            *(uint4*)&sAl[swzo(sr, sc + 1)] = al1;
        }
        asm volatile("s_waitcnt vmcnt(0)" ::: "memory");
        __syncthreads();

        const int kn = k0 + 32;
        if (kn < K) {
            *(float4*)&fv[0]  = *(const float4*)(Ap + kn);
            *(float4*)&fv[4]  = *(const float4*)(Ap + kn + 4);
            *(float4*)&fv[8]  = *(const float4*)(Ap + kn + 8);
            *(float4*)&fv[12] = *(const float4*)(Ap + kn + 12);
        }

        f16x8 ah[4], al[4], bh[4];
#pragma unroll
        for (int f = 0; f < 4; f++) {
            const int off = swzo(wm + f * 16 + lr, lk);
            ah[f] = *(const f16x8*)&sAh[off];
            if (AT == 2) al[f] = *(const f16x8*)&sAl[off];
            bh[f] = *(const f16x8*)&sBh[swzo(wn + f * 16 + lr, lk)];
        }
#pragma unroll
        for (int fm = 0; fm < 4; fm++)
#pragma unroll
            for (int fn = 0; fn < 4; fn++) {
                acc[fm][fn] = __builtin_amdgcn_mfma_f32_16x16x32_f16(ah[fm], bh[fn], acc[fm][fn], 0, 0, 0);
                if (AT == 2)
                    acc[fm][fn] = __builtin_amdgcn_mfma_f32_16x16x32_f16(al[fm], bh[fn], acc[fm][fn], 0, 0, 0);
            }
    }
#pragma unroll
    for (int fm = 0; fm < 4; fm++) {
        const int mrow = m0 + wm + fm * 16 + lk * 4;
#pragma unroll
        for (int fn = 0; fn < 4; fn++) {
            const int col = n0 + wn + fn * 16 + lr;
            const float bv = bias[col];
#pragma unroll
            for (int j = 0; j < 4; j++) {
                float v = acc[fm][fn][j] + bv;
                if (RELU) v = fmaxf(v, 0.0f);
                const u16 h = f2h_(v);
                Chi[(size_t)(mrow + j) * N + col] = h;
                if (WSPLIT) Clo[(size_t)(mrow + j) * N + col] = f2h_(v - h2f_(h));
            }
        }
    }
}

// FUSED enc1: ids [0,1024) = edge (AT1), ids [1024,1088) = obj (AT2, split out)
__global__ __launch_bounds__(256, 3) void enc1_both(
    const float* __restrict__ xp, const u16* __restrict__ pw,
    const float* __restrict__ pb, u16* __restrict__ tmpe,
    const float* __restrict__ xo, const u16* __restrict__ ow,
    const float* __restrict__ ob, u16* __restrict__ tmpoh, u16* __restrict__ tmpol)
{
    __shared__ u16 smem[3 * 4096];
    const int id = xcdswz(blockIdx.x, gridDim.x);
    if (id < 1024)
        gemm_a32_body<true, 1, false>(id, smem, smem + 4096, nullptr,
                                      xp, pw, pb, tmpe, nullptr, 4, D_IN);
    else
        gemm_a32_body<true, 2, true>(id - 1024, smem, smem + 4096, smem + 8192,
                                     xo, ow, ob, tmpoh, tmpol, 4, D_IN);
}

// ---------------------------------------------------------------------------
// BODY: f16 GEMM, A presplit (hi [+lo if AT=2]), B f16; all via gload_lds.
// BK=64. LDS: sA0=0, sA1=4096, sB0=8192, sB1=12288, [sL0=16384, sL1=20480].
// ---------------------------------------------------------------------------
template<int AT, bool WF32, bool WHI, bool WLO>
__device__ __forceinline__ void gemm_f16_body(
    int id, u16* smem,
    const u16* __restrict__ Ahi, const u16* __restrict__ Alo,
    const u16* __restrict__ Bhi, const float* __restrict__ bias,
    float* __restrict__ C32, u16* __restrict__ Chi, u16* __restrict__ Clo,
    int NX, int N, int ldc, int K)
{
    const int m0 = (id / NX) * 128, n0 = (id % NX) * 128;
    const int t = threadIdx.x;
    const int wid = t >> 6, lane = t & 63;
    const int wm = (wid >> 1) * 64, wn = (wid & 1) * 64;
    const int lr = lane & 15, lk = lane >> 4;

    f32x4 acc[4][4] = {};

    const int rr = (wid * 2) * 16 + (lane >> 2);
    const int cc = (lane & 3) ^ ((rr >> 1) & 3);
    const u16* pA0 = Ahi + (size_t)(m0 + rr) * K + cc * 8;
    const u16* pA1 = pA0 + (size_t)16 * K;
    const u16* pL0 = (AT == 2) ? Alo + (size_t)(m0 + rr) * K + cc * 8 : nullptr;
    const u16* pL1 = (AT == 2) ? pL0 + (size_t)16 * K : nullptr;
    const u16* pB0 = Bhi + (size_t)(n0 + rr) * K + cc * 8;
    const u16* pB1 = pB0 + (size_t)16 * K;
    const int bOff = (wid * 2) * 512;

    for (int k0 = 0; k0 < K; k0 += 64) {
        __syncthreads();
#pragma unroll
        for (int h = 0; h < 2; h++) {
            const int kk = k0 + h * 32;
            u16* sA_ = smem + h * 4096;
            u16* sB_ = smem + 8192 + h * 4096;
            gload16(pA0 + kk, sA_ + bOff);
            gload16(pA1 + kk, sA_ + bOff + 512);
            if (AT == 2) {
                u16* sL_ = smem + 16384 + h * 4096;
                gload16(pL0 + kk, sL_ + bOff);
                gload16(pL1 + kk, sL_ + bOff + 512);
            }
            gload16(pB0 + kk, sB_ + bOff);
            gload16(pB1 + kk, sB_ + bOff + 512);
        }
        asm volatile("s_waitcnt vmcnt(0)" ::: "memory");
        __syncthreads();

#pragma unroll
        for (int h = 0; h < 2; h++) {
            const u16* sA_ = smem + h * 4096;
            const u16* sB_ = smem + 8192 + h * 4096;
            const u16* sL_ = smem + 16384 + h * 4096;
            f16x8 ah[4], al[4], bh[4];
#pragma unroll
            for (int f = 0; f < 4; f++) {
                const int off = swzo(wm + f * 16 + lr, lk);
                ah[f] = *(const f16x8*)&sA_[off];
                if (AT == 2) al[f] = *(const f16x8*)&sL_[off];
                bh[f] = *(const f16x8*)&sB_[swzo(wn + f * 16 + lr, lk)];
            }
#pragma unroll
            for (int fm = 0; fm < 4; fm++)
#pragma unroll
                for (int fn = 0; fn < 4; fn++) {
                    acc[fm][fn] = __builtin_amdgcn_mfma_f32_16x16x32_f16(ah[fm], bh[fn], acc[fm][fn], 0, 0, 0);
                    if (AT == 2)
                        acc[fm][fn] = __builtin_amdgcn_mfma_f32_16x16x32_f16(al[fm], bh[fn], acc[fm][fn], 0, 0, 0);
                }
        }
    }
#pragma unroll
    for (int fm = 0; fm < 4; fm++) {
        const int mrow = m0 + wm + fm * 16 + lk * 4;
#pragma unroll
        for (int fn = 0; fn < 4; fn++) {
            const int col = n0 + wn + fn * 16 + lr;
            const float bv = bias[col];
#pragma unroll
            for (int j = 0; j < 4; j++) {
                const float v = acc[fm][fn][j] + bv;
                if (WF32 && col < N) C32[(size_t)(mrow + j) * ldc + col] = v;
                if (WHI) {
                    const u16 h = f2h_(v);
                    Chi[(size_t)(mrow + j) * (NX * 128) + col] = h;
                    if (WLO)
                        Clo[(size_t)(mrow + j) * (NX * 128) + col] = f2h_(v - h2f_(h));
                }
            }
        }
    }
}

// Standalone presplit GEMM kernels (enc2)
template<int AT, bool WF32, bool WHI, bool WLO>
__global__ __launch_bounds__(256, AT == 1 ? 4 : 3) void gemm_f16(
    const u16* __restrict__ Ahi, const u16* __restrict__ Alo,
    const u16* __restrict__ Bhi, const float* __restrict__ bias,
    float* __restrict__ C32, u16* __restrict__ Chi, u16* __restrict__ Clo,
    int NX, int N, int ldc, int K)
{
    __shared__ u16 smem[AT == 2 ? 6 * 4096 : 4 * 4096];
    const int id = xcdswz(blockIdx.x, gridDim.x);
    gemm_f16_body<AT, WF32, WHI, WLO>(id, smem, Ahi, Alo, Bhi, bias,
                                      C32, Chi, Clo, NX, N, ldc, K);
}

// FUSED classifiers: ids [0,256) = edge cls (AT1), [256,288) = obj cls (AT2)
__global__ __launch_bounds__(256, 3) void cls_both(
    const u16* __restrict__ hhe, const u16* __restrict__ pph,
    const float* __restrict__ ppb, float* __restrict__ plog,
    const u16* __restrict__ hhoh, const u16* __restrict__ hhol,
    const u16* __restrict__ oph, const float* __restrict__ opb,
    float* __restrict__ olog)
{
    __shared__ u16 smem[6 * 4096];
    const int id = xcdswz(blockIdx.x, gridDim.x);
    if (id < 256)
        gemm_f16_body<1, true, false, false>(id, smem, hhe, nullptr, pph, ppb,
                                             plog, nullptr, nullptr,
                                             1, N_REL_CLS, N_REL_CLS, DIM);
    else
        gemm_f16_body<2, true, false, false>(id - 256, smem, hhoh, hhol, oph, opb,
                                             olog, nullptr, nullptr,
                                             2, N_OBJ_CLS, N_OBJ_CLS, DIM);
}

// ---------------------------------------------------------------------------
// BODY: GRU panel GEMM. A = concat(X[0:512], H[0:512]) along K (pointer
// switch at k=512, sub-tile-uniform). A row stride fixed DIM; B stride = K;
// C row stride fixed GOUT (C pre-offset by panel column base). AT terms.
// ---------------------------------------------------------------------------
template<int AT>
__device__ __forceinline__ void gru_body(
    int m0b, int nblk, u16* smem,
    const u16* __restrict__ Xh, const u16* __restrict__ Xl,
    const u16* __restrict__ Hh, const u16* __restrict__ Hl,
    const u16* __restrict__ B, const float* __restrict__ bias,
    u16* __restrict__ C, int K)
{
    const int m0 = m0b * 128, n0 = nblk * 128;
    const int t = threadIdx.x;
    const int wid = t >> 6, lane = t & 63;
    const int wm = (wid >> 1) * 64, wn = (wid & 1) * 64;
    const int lr = lane & 15, lk = lane >> 4;

    f32x4 acc[4][4] = {};

    const int rr = (wid * 2) * 16 + (lane >> 2);
    const int cc = (lane & 3) ^ ((rr >> 1) & 3);
    const size_t arow = (size_t)(m0 + rr) * DIM + cc * 8;
    const u16* pX0 = Xh + arow; const u16* pX1 = pX0 + 16 * DIM;
    const u16* pXl0 = (AT == 2) ? Xl + arow : nullptr;
    const u16* pXl1 = (AT == 2) ? pXl0 + 16 * DIM : nullptr;
    const u16* pH0 = Hh + arow; const u16* pH1 = pH0 + 16 * DIM;
    const u16* pHl0 = (AT == 2) ? Hl + arow : nullptr;
    const u16* pHl1 = (AT == 2) ? pHl0 + 16 * DIM : nullptr;
    const u16* pB0 = B + (size_t)(n0 + rr) * K + cc * 8;
    const u16* pB1 = pB0 + (size_t)16 * K;
    const int bOff = (wid * 2) * 512;

    for (int k0 = 0; k0 < K; k0 += 64) {
        __syncthreads();
#pragma unroll
        for (int h = 0; h < 2; h++) {
            const int kk = k0 + h * 32;
            const bool inX = kk < 512;
            const int ka = inX ? kk : kk - 512;
            u16* sA_ = smem + h * 4096;
            u16* sB_ = smem + 8192 + h * 4096;
            gload16((inX ? pX0 : pH0) + ka, sA_ + bOff);
            gload16((inX ? pX1 : pH1) + ka, sA_ + bOff + 512);
            if (AT == 2) {
                u16* sL_ = smem + 16384 + h * 4096;
                gload16((inX ? pXl0 : pHl0) + ka, sL_ + bOff);
                gload16((inX ? pXl1 : pHl1) + ka, sL_ + bOff + 512);
            }
            gload16(pB0 + kk, sB_ + bOff);
            gload16(pB1 + kk, sB_ + bOff + 512);
        }
        asm volatile("s_waitcnt vmcnt(0)" ::: "memory");
        __syncthreads();

#pragma unroll
        for (int h = 0; h < 2; h++) {
            const u16* sA_ = smem + h * 4096;
            const u16* sB_ = smem + 8192 + h * 4096;
            const u16* sL_ = smem + 16384 + h * 4096;
            f16x8 ah[4], al[4], bh[4];
#pragma unroll
            for (int f = 0; f < 4; f++) {
                const int off = swzo(wm + f * 16 + lr, lk);
                ah[f] = *(const f16x8*)&sA_[off];
                if (AT == 2) al[f] = *(const f16x8*)&sL_[off];
                bh[f] = *(const f16x8*)&sB_[swzo(wn + f * 16 + lr, lk)];
            }
#pragma unroll
            for (int fm = 0; fm < 4; fm++)
#pragma unroll
                for (int fn = 0; fn < 4; fn++) {
                    acc[fm][fn] = __builtin_amdgcn_mfma_f32_16x16x32_f16(ah[fm], bh[fn], acc[fm][fn], 0, 0, 0);
                    if (AT == 2)
                        acc[fm][fn] = __builtin_amdgcn_mfma_f32_16x16x32_f16(al[fm], bh[fn], acc[fm][fn], 0, 0, 0);
                }
        }
    }
#pragma unroll
    for (int fm = 0; fm < 4; fm++) {
        const int mrow = m0 + wm + fm * 16 + lk * 4;
#pragma unroll
        for (int fn = 0; fn < 4; fn++) {
            const int col = n0 + wn + fn * 16 + lr;
            const float bv = bias[col];
#pragma unroll
            for (int j = 0; j < 4; j++)
                C[(size_t)(mrow + j) * GOUT + col] = f2h_(acc[fm][fn][j] + bv);
        }
    }
}

// Merged GRU GEMM v3: parts 0-7 rz (K=1024, A=[X|H], B=Wrz packed, bias=brz);
// parts 8-11 in (K=512, A=X, B=Wih n-rows); parts 12-15 hn (K=512, A=H).
// Output C [rows][GOUT] = [rz 1024 | in 512 | hn 512].
template<int AT>
__global__ __launch_bounds__(256, AT == 1 ? 4 : 3) void gru_gemm3(
    const u16* __restrict__ Xh, const u16* __restrict__ Xl,
    const u16* __restrict__ Hh, const u16* __restrict__ Hl,
    const u16* __restrict__ Wrz, const float* __restrict__ brz,
    const u16* __restrict__ Wni, const float* __restrict__ bni,
    const u16* __restrict__ Wnh, const float* __restrict__ bnh,
    u16* __restrict__ C)
{
    __shared__ u16 smem[AT == 2 ? 6 * 4096 : 4 * 4096];
    const int id = xcdswz(blockIdx.x, gridDim.x);
    const int part = id % 16;
    const int m0b = id / 16;
    if (part < 8)
        gru_body<AT>(m0b, part, smem, Xh, Xl, Hh, Hl, Wrz, brz, C, 1024);
    else if (part < 12)
        gru_body<AT>(m0b, part - 8, smem, Xh, Xl, Xh, Xl, Wni, bni, C + 1024, 512);
    else
        gru_body<AT>(m0b, part - 12, smem, Hh, Hl, Hh, Hl, Wnh, bnh, C + 1536, 512);
}

// ---------------------------------------------------------------------------
// GRU combine v3: g [R x GOUT] = [rz_sum | in | hn]; h from f16 shadow.
// ---------------------------------------------------------------------------
__device__ __forceinline__ float gcomb2(u16 rzr, u16 rzz, u16 in_, u16 hn, float h) {
    const float r = sigmoidf_(h2f_(rzr));
    const float z = sigmoidf_(h2f_(rzz));
    const float n = tanhf(h2f_(in_) + r * h2f_(hn));
    return (1.0f - z) * n + z * h;
}

template<bool WSPLIT, bool WF32>
__global__ __launch_bounds__(256) void gru_combine2(
    const u16* __restrict__ g, u16* __restrict__ hh, u16* __restrict__ hl,
    float* __restrict__ H32, int R)
{
    const int idx = blockIdx.x * 256 + threadIdx.x;      // R*128 quads
    if (idx >= R * 128) return;
    const int r = idx >> 7, c4 = (idx & 127) * 4;
    const size_t gb = (size_t)r * GOUT + c4;
    const ushort4 r4 = *(const ushort4*)&g[gb];
    const ushort4 z4 = *(const ushort4*)&g[gb + 512];
    const ushort4 in4 = *(const ushort4*)&g[gb + 1024];
    const ushort4 hn4 = *(const ushort4*)&g[gb + 1536];
    const size_t hb = (size_t)r * 512 + c4;
    const ushort4 hhi = *(const ushort4*)&hh[hb];
    float h0 = h2f_(hhi.x), h1 = h2f_(hhi.y), h2 = h2f_(hhi.z), h3 = h2f_(hhi.w);
    if (WSPLIT) {
        const ushort4 hlo = *(const ushort4*)&hl[hb];
        h0 += h2f_(hlo.x); h1 += h2f_(hlo.y); h2 += h2f_(hlo.z); h3 += h2f_(hlo.w);
    }
    float4 o;
    o.x = gcomb2(r4.x, z4.x, in4.x, hn4.x, h0);
    o.y = gcomb2(r4.y, z4.y, in4.y, hn4.y, h1);
    o.z = gcomb2(r4.z, z4.z, in4.z, hn4.z, h2);
    o.w = gcomb2(r4.w, z4.w, in4.w, hn4.w, h3);
    const ushort4 hi4 = make_ushort4(f2h_(o.x), f2h_(o.y), f2h_(o.z), f2h_(o.w));
    *(ushort4*)&hh[hb] = hi4;
    if (WSPLIT) {
        *(ushort4*)&hl[hb] = make_ushort4(
            f2h_(o.x - h2f_(hi4.x)), f2h_(o.y - h2f_(hi4.y)),
            f2h_(o.z - h2f_(hi4.z)), f2h_(o.w - h2f_(hi4.w)));
    }
    if (WF32) *(float4*)&H32[hb] = o;
}

// ---------------------------------------------------------------------------
// CSR build
// ---------------------------------------------------------------------------
__global__ __launch_bounds__(256) void count_int(const int* __restrict__ rel,
                                                 int* cs, int* co)
{
    const int e = blockIdx.x * 256 + threadIdx.x;
    atomicAdd(&cs[rel[2 * e]], 1);
    atomicAdd(&co[rel[2 * e + 1]], 1);
}

__global__ __launch_bounds__(256) void scan_off(const int* __restrict__ cs,
    const int* __restrict__ co, int* __restrict__ offs, int* __restrict__ offo)
{
    __shared__ int tmp[256];
    for (int arr = 0; arr < 2; arr++) {
        const int* c = arr ? co : cs;
        int* off = arr ? offo : offs;
        const int base = threadIdx.x * 8;
        int loc[8]; int s = 0;
#pragma unroll
        for (int j = 0; j < 8; j++) { loc[j] = c[base + j]; s += loc[j]; }
        tmp[threadIdx.x] = s;
        __syncthreads();
        for (int d = 1; d < 256; d <<= 1) {
            const int v = (threadIdx.x >= d) ? tmp[threadIdx.x - d] : 0;
            __syncthreads();
            tmp[threadIdx.x] += v;
            __syncthreads();
        }
        int p = tmp[threadIdx.x] - s;    // exclusive prefix
#pragma unroll
        for (int j = 0; j < 8; j++) { off[base + j] = p; p += loc[j]; }
        __syncthreads();
    }
}

__global__ __launch_bounds__(256) void fill_csr(const int* __restrict__ rel,
    int* curS, int* curO, const int* __restrict__ offs, const int* __restrict__ offo,
    int* __restrict__ listS, int* __restrict__ listO)
{
    const int e = blockIdx.x * 256 + threadIdx.x;
    const int s = rel[2 * e], o = rel[2 * e + 1];
    const int i = atomicAdd(&curS[s], 1);
    listS[offs[s] + i] = e;
    const int j = atomicAdd(&curO[o], 1);
    listO[offo[o] + j] = e;
}

// ---------------------------------------------------------------------------
// Gates + edge messages, one WAVE per edge (no barrier, no atomics).
// ---------------------------------------------------------------------------
__global__ __launch_bounds__(256) void gatepass(
    const u16* __restrict__ hho, const u16* __restrict__ hhe,
    const int* __restrict__ rel,
    const float* __restrict__ wsn, const float* __restrict__ bsn,
    const float* __restrict__ won, const float* __restrict__ bon,
    const float* __restrict__ wse, const float* __restrict__ bse,
    const float* __restrict__ woe, const float* __restrict__ boe,
    const int* __restrict__ cs, const int* __restrict__ co,
    u16* __restrict__ emh, float* __restrict__ af, float* __restrict__ ag)
{
    const int e = blockIdx.x * 4 + (threadIdx.x >> 6);
    const int lane = threadIdx.x & 63;
    const int s = rel[2 * e], o = rel[2 * e + 1];
    const int c = lane * 8;

    const uint4 hsu = *(const uint4*)&hho[(size_t)s * DIM + c];
    const uint4 hou = *(const uint4*)&hho[(size_t)o * DIM + c];
    const uint4 heu = *(const uint4*)&hhe[(size_t)e * DIM + c];
    float hs[8], ho[8], he[8];
    hs[0] = h2f_((u16)hsu.x); hs[1] = h2f_((u16)(hsu.x >> 16));
    hs[2] = h2f_((u16)hsu.y); hs[3] = h2f_((u16)(hsu.y >> 16));
    hs[4] = h2f_((u16)hsu.z); hs[5] = h2f_((u16)(hsu.z >> 16));
    hs[6] = h2f_((u16)hsu.w); hs[7] = h2f_((u16)(hsu.w >> 16));
    ho[0] = h2f_((u16)hou.x); ho[1] = h2f_((u16)(hou.x >> 16));
    ho[2] = h2f_((u16)hou.y); ho[3] = h2f_((u16)(hou.y >> 16));
    ho[4] = h2f_((u16)hou.z); ho[5] = h2f_((u16)(hou.z >> 16));
    ho[6] = h2f_((u16)hou.w); ho[7] = h2f_((u16)(hou.w >> 16));
    he[0] = h2f_((u16)heu.x); he[1] = h2f_((u16)(heu.x >> 16));
    he[2] = h2f_((u16)heu.y); he[3] = h2f_((u16)(heu.y >> 16));
    he[4] = h2f_((u16)heu.z); he[5] = h2f_((u16)(heu.z >> 16));
    he[6] = h2f_((u16)heu.w); he[7] = h2f_((u16)(heu.w >> 16));

    float p0 = 0.f, p1 = 0.f, p2 = 0.f, p3 = 0.f;
#pragma unroll
    for (int q = 0; q < 2; q++) {
        const float4 w0v = *(const float4*)&wsn[c + q * 4];
        const float4 w0e = *(const float4*)&wsn[DIM + c + q * 4];
        const float4 w1v = *(const float4*)&won[c + q * 4];
        const float4 w1e = *(const float4*)&won[DIM + c + q * 4];
        const float4 w2v = *(const float4*)&wse[c + q * 4];
        const float4 w2e = *(const float4*)&wse[DIM + c + q * 4];
        const float4 w3v = *(const float4*)&woe[c + q * 4];
        const float4 w3e = *(const float4*)&woe[DIM + c + q * 4];
        const float* s4 = &hs[q * 4];
        const float* o4 = &ho[q * 4];
        const float* e4 = &he[q * 4];
        p0 += s4[0]*w0v.x + s4[1]*w0v.y + s4[2]*w0v.z + s4[3]*w0v.w
            + e4[0]*w0e.x + e4[1]*w0e.y + e4[2]*w0e.z + e4[3]*w0e.w;
        p1 += o4[0]*w1v.x + o4[1]*w1v.y + o4[2]*w1v.z + o4[3]*w1v.w
            + e4[0]*w1e.x + e4[1]*w1e.y + e4[2]*w1e.z + e4[3]*w1e.w;
        p2 += s4[0]*w2v.x + s4[1]*w2v.y + s4[2]*w2v.z + s4[3]*w2v.w
            + e4[0]*w2e.x + e4[1]*w2e.y + e4[2]*w2e.z + e4[3]*w2e.w;
        p3 += o4[0]*w3v.x + o4[1]*w3v.y + o4[2]*w3v.z + o4[3]*w3v.w
            + e4[0]*w3e.x + e4[1]*w3e.y + e4[2]*w3e.z + e4[3]*w3e.w;
    }
#pragma unroll
    for (int off = 32; off; off >>= 1) {
        p0 += __shfl_xor(p0, off);
        p1 += __shfl_xor(p1, off);
        p2 += __shfl_xor(p2, off);
        p3 += __shfl_xor(p3, off);
    }
    const float gsn = sigmoidf_(p0 + bsn[0]);
    const float gon = sigmoidf_(p1 + bon[0]);
    const float gse = sigmoidf_(p2 + bse[0]);
    const float goe = sigmoidf_(p3 + boe[0]);

    if (lane == 0) {
        af[e] = 0.5f * gsn / ((float)cs[s] + EPSV);
        ag[e] = 0.5f * gon / ((float)co[o] + EPSV);
    }
    u16 em8[8];
#pragma unroll
    for (int j = 0; j < 8; j++)
        em8[j] = f2h_(0.5f * (gse * hs[j] + goe * ho[j]));
    *(uint4*)&emh[(size_t)e * DIM + c] = *(const uint4*)em8;
}

// ---------------------------------------------------------------------------
// Node-message gather (no atomics), reading f16 h_edge shadow.
// ---------------------------------------------------------------------------
__global__ __launch_bounds__(256) void gather_nm(
    const u16* __restrict__ hhe,
    const int* __restrict__ listS, const int* __restrict__ listO,
    const int* __restrict__ offs, const int* __restrict__ offo,
    const int* __restrict__ cs, const int* __restrict__ co,
    const float* __restrict__ af, const float* __restrict__ ag,
    u16* __restrict__ nmh, u16* __restrict__ nml)
{
    const int v = blockIdx.x * 4 + (threadIdx.x >> 6);
    const int lane = threadIdx.x & 63;
    const int c = lane * 8;

    float acc[8] = {};
#pragma unroll
    for (int side = 0; side < 2; side++) {
        const int* list = side ? listO : listS;
        const int b = side ? offo[v] : offs[v];
        const int n = side ? co[v] : cs[v];
        const float* coef = side ? ag : af;
        for (int i = 0; i < n; i++) {
            const int e = list[b + i];
            const float a = coef[e];
            const uint4 x = *(const uint4*)&hhe[(size_t)e * DIM + c];
            acc[0] += a * h2f_((u16)x.x); acc[1] += a * h2f_((u16)(x.x >> 16));
            acc[2] += a * h2f_((u16)x.y); acc[3] += a * h2f_((u16)(x.y >> 16));
            acc[4] += a * h2f_((u16)x.z); acc[5] += a * h2f_((u16)(x.z >> 16));
            acc[6] += a * h2f_((u16)x.w); acc[7] += a * h2f_((u16)(x.w >> 16));
        }
    }
    u16 hi8[8], lo8[8];
#pragma unroll
    for (int j = 0; j < 8; j++) {
        hi8[j] = f2h_(acc[j]);
        lo8[j] = f2h_(acc[j] - h2f_(hi8[j]));
    }
    *(uint4*)&nmh[(size_t)v * DIM + c] = *(const uint4*)hi8;
    *(uint4*)&nml[(size_t)v * DIM + c] = *(const uint4*)lo8;
}

// ---------------------------------------------------------------------------
__global__ __launch_bounds__(256) void argmax_kernel(const float* __restrict__ logits,
                                                     float* __restrict__ out)
{
    const int row = blockIdx.x * 4 + (threadIdx.x >> 6);
    const int lane = threadIdx.x & 63;
    float bv = -1e30f; int bi = 1;
    for (int j = 1 + lane; j < N_OBJ_CLS; j += 64) {
        const float v = logits[(size_t)row * N_OBJ_CLS + j];
        if (v > bv) { bv = v; bi = j; }
    }
#pragma unroll
    for (int off = 32; off; off >>= 1) {
        const float ov = __shfl_xor(bv, off);
        const int oi = __shfl_xor(bi, off);
        if (ov > bv || (ov == bv && oi < bi)) { bv = ov; bi = oi; }
    }
    if (lane == 0) out[row] = (float)bi;
}

__global__ __launch_bounds__(256) void relinds_kernel(const int* __restrict__ rel,
                                                      float* __restrict__ out)
{
    const int i = blockIdx.x * 256 + threadIdx.x;
    out[i] = (float)rel[i];
}

// ---------------------------------------------------------------------------
extern "C" void kernel_launch(void* const* d_in, const int* in_sizes, int n_in,
                              void* d_out, int out_size, void* d_ws, size_t ws_size,
                              hipStream_t stream)
{
    const float* x_obj = (const float*)d_in[0];
    const float* x_pred = (const float*)d_in[1];
    const int* rel = (const int*)d_in[2];
    const float* oe_w1 = (const float*)d_in[3];
    const float* oe_b1 = (const float*)d_in[4];
    const float* oe_w2 = (const float*)d_in[5];
    const float* oe_b2 = (const float*)d_in[6];
    const float* pe_w1 = (const float*)d_in[7];
    const float* pe_b1 = (const float*)d_in[8];
    const float* pe_w2 = (const float*)d_in[9];
    const float* pe_b2 = (const float*)d_in[10];
    const float* g_sn_w = (const float*)d_in[11];
    const float* g_sn_b = (const float*)d_in[12];
    const float* g_on_w = (const float*)d_in[13];
    const float* g_on_b = (const float*)d_in[14];
    const float* g_se_w = (const float*)d_in[15];
    const float* g_se_b = (const float*)d_in[16];
    const float* g_oe_w = (const float*)d_in[17];
    const float* g_oe_b = (const float*)d_in[18];
    const float* ngru_wih = (const float*)d_in[19];
    const float* ngru_whh = (const float*)d_in[20];
    const float* ngru_bih = (const float*)d_in[21];
    const float* ngru_bhh = (const float*)d_in[22];
    const float* egru_wih = (const float*)d_in[23];
    const float* egru_whh = (const float*)d_in[24];
    const float* egru_bih = (const float*)d_in[25];
    const float* egru_bhh = (const float*)d_in[26];
    const float* op_w = (const float*)d_in[27];
    const float* op_b = (const float*)d_in[28];
    const float* pp_w = (const float*)d_in[29];
    const float* pp_b = (const float*)d_in[30];

    float* out = (float*)d_out;

    float* h_obj = out + OFF_HOBJ;       // f32 state written only at final step
    float* h_edge = out + OFF_HEDGE;

    // ---- workspace layout ----
    char* wsp = (char*)d_ws;
    float* af = (float*)wsp; wsp += N_RELS * 4;
    float* ag = (float*)wsp; wsp += N_RELS * 4;
    float* brz_n = (float*)wsp; wsp += 1024 * 4;
    float* brz_e = (float*)wsp; wsp += 1024 * 4;
    int* cs = (int*)wsp;   wsp += N_OBJS * 4;
    int* co = (int*)wsp;   wsp += N_OBJS * 4;
    int* offs = (int*)wsp; wsp += N_OBJS * 4;
    int* offo = (int*)wsp; wsp += N_OBJS * 4;
    int* curS = (int*)wsp; wsp += N_OBJS * 4;
    int* curO = (int*)wsp; wsp += N_OBJS * 4;
    int* listS = (int*)wsp; wsp += N_RELS * 4;
    int* listO = (int*)wsp; wsp += N_RELS * 4;

    u16* wp = (u16*)wsp;
    const int s_big = DIM * D_IN, s_sq = DIM * DIM, s_gru = 3 * DIM * DIM;
    // weights (f16)
    u16 *oe1h = wp; wp += s_big;
    u16 *pe1h = wp; wp += s_big;
    u16 *oe2h = wp; wp += s_sq;
    u16 *pe2h = wp; wp += s_sq;
    u16 *nih_h = wp; wp += s_gru;
    u16 *nhh_h = wp; wp += s_gru;
    u16 *eih_h = wp; wp += s_gru;
    u16 *ehh_h = wp; wp += s_gru;
    u16 *oph = wp; wp += 256 * DIM;
    u16 *pph = wp; wp += 128 * DIM;
    u16 *wrz_n = wp; wp += 1024 * 1024;   // packed [Wih_rz | Whh_rz]
    u16 *wrz_e = wp; wp += 1024 * 1024;
    // f16 activations
    u16 *tmpo_h = wp; wp += (size_t)N_OBJS * DIM;   // enc1-obj out hi
    u16 *tmpo_l = wp; wp += (size_t)N_OBJS * DIM;   // enc1-obj out lo
    u16 *tmpe_h = wp; wp += (size_t)N_RELS * DIM;   // enc1-edge out (1-term)
    u16 *hhoh = wp; wp += (size_t)N_OBJS * DIM;     // h_obj shadow hi
    u16 *hhol = wp; wp += (size_t)N_OBJS * DIM;     // h_obj shadow lo
    u16 *hhe  = wp; wp += (size_t)N_RELS * DIM;     // h_edge shadow (1-term)
    u16 *emh  = wp; wp += (size_t)N_RELS * DIM;     // edge messages f16
    u16 *nmh  = wp; wp += (size_t)N_OBJS * DIM;     // node messages hi
    u16 *nml  = wp; wp += (size_t)N_OBJS * DIM;     // node messages lo

    // packed gate buffer (f16, R x GOUT)
    const size_t used = (size_t)((char*)wp - (char*)d_ws);
    int R = 8192;
    if (used + (size_t)16384 * (GOUT * 2) <= ws_size) R = 16384;
    u16* gcat = wp;

    auto cvtw = [&](const float* s, u16* h, int n) {
        convert_h<<<(n / 4 + 255) / 256, 256, 0, stream>>>(s, h, n / 4);
    };
    cvtw(oe_w1, oe1h, s_big);
    cvtw(pe_w1, pe1h, s_big);
    cvtw(oe_w2, oe2h, s_sq);
    cvtw(pe_w2, pe2h, s_sq);
    cvtw(ngru_wih, nih_h, s_gru);
    cvtw(ngru_whh, nhh_h, s_gru);
    cvtw(egru_wih, eih_h, s_gru);
    cvtw(egru_whh, ehh_h, s_gru);
    cvtw(op_w, oph, N_OBJ_CLS * DIM);
    cvtw(pp_w, pph, N_REL_CLS * DIM);
    // pack rz weights/biases (reads f16 weights -> stream-ordered after cvtw)
    pack_rz<<<512, 256, 0, stream>>>(nih_h, nhh_h, wrz_n);
    pack_rz<<<512, 256, 0, stream>>>(eih_h, ehh_h, wrz_e);
    pack_brz<<<4, 256, 0, stream>>>(ngru_bih, ngru_bhh, brz_n);
    pack_brz<<<4, 256, 0, stream>>>(egru_bih, egru_bhh, brz_e);

    // CSR build
    hipMemsetAsync(cs, 0, 2 * N_OBJS * sizeof(int), stream);
    hipMemsetAsync(curS, 0, 2 * N_OBJS * sizeof(int), stream);
    count_int<<<N_RELS / 256, 256, 0, stream>>>(rel, cs, co);
    scan_off<<<1, 256, 0, stream>>>(cs, co, offs, offo);
    fill_csr<<<N_RELS / 256, 256, 0, stream>>>(rel, curS, curO, offs, offo, listS, listO);

    // enc1: FUSED edge(1-term) + obj(2-term split-out) in one launch
    enc1_both<<<1088, 256, 0, stream>>>(
        x_pred, pe1h, pe_b1, tmpe_h,
        x_obj, oe1h, oe_b1, tmpo_h, tmpo_l);
    // enc2: separate (preserves edge AT1 occupancy)
    gemm_f16<1, false, true, false><<<4 * (N_RELS / 128), 256, 0, stream>>>(
        tmpe_h, nullptr, pe2h, pe_b2, nullptr, hhe, nullptr, 4, DIM, DIM, DIM);
    gemm_f16<2, false, true, true><<<4 * (N_OBJS / 128), 256, 0, stream>>>(
        tmpo_h, tmpo_l, oe2h, oe_b2, nullptr, hhoh, hhol, 4, DIM, DIM, DIM);

    // message-passing steps (f16 state between steps; f32 out at last step)
    for (int step = 0; step < 2; step++) {
        gatepass<<<N_RELS / 4, 256, 0, stream>>>(
            hhoh, hhe, rel,
            g_sn_w, g_sn_b, g_on_w, g_on_b, g_se_w, g_se_b, g_oe_w, g_oe_b,
            cs, co, emh, af, ag);
        gather_nm<<<N_OBJS / 4, 256, 0, stream>>>(
            hhe, listS, listO, offs, offo, cs, co, af, ag, nmh, nml);

        // obj GRU (2-term): packed-panel GEMM + combine
        gru_gemm3<2><<<16 * (N_OBJS / 128), 256, 0, stream>>>(
            nmh, nml, hhoh, hhol, wrz_n, brz_n,
            nih_h + 1024 * DIM, ngru_bih + 1024,
            nhh_h + 1024 * DIM, ngru_bhh + 1024, gcat);
        if (step == 0)
            gru_combine2<true, false><<<(N_OBJS * 128 + 255) / 256, 256, 0, stream>>>(
                gcat, hhoh, hhol, nullptr, N_OBJS);
        else
            gru_combine2<true, true><<<(N_OBJS * 128 + 255) / 256, 256, 0, stream>>>(
                gcat, hhoh, hhol, h_obj, N_OBJS);

        // edge GRU (1-term), chunked
        for (int r0 = 0; r0 < N_RELS; r0 += R) {
            const int Rc = (N_RELS - r0 < R) ? (N_RELS - r0) : R;
            gru_gemm3<1><<<16 * (Rc / 128), 256, 0, stream>>>(
                emh + (size_t)r0 * DIM, nullptr, hhe + (size_t)r0 * DIM, nullptr,
                wrz_e, brz_e,
                eih_h + 1024 * DIM, egru_bih + 1024,
                ehh_h + 1024 * DIM, egru_bhh + 1024, gcat);
            if (step == 0)
                gru_combine2<false, false><<<(Rc * 128 + 255) / 256, 256, 0, stream>>>(
                    gcat, hhe + (size_t)r0 * DIM, nullptr, nullptr, Rc);
            else
                gru_combine2<false, true><<<(Rc * 128 + 255) / 256, 256, 0, stream>>>(
                    gcat, hhe + (size_t)r0 * DIM, nullptr, h_edge + (size_t)r0 * DIM, Rc);
        }
    }

    // classifiers: FUSED edge(1-term) + obj(2-term, labels) in one launch
    cls_both<<<288, 256, 0, stream>>>(
        hhe, pph, pp_b, out + OFF_PLOG,
        hhoh, hhol, oph, op_b, out + OFF_OLOG);

    // labels + rel_inds passthrough
    argmax_kernel<<<N_OBJS / 4, 256, 0, stream>>>(out + OFF_OLOG, out + OFF_LBL);
    relinds_kernel<<<(2 * N_RELS) / 256, 256, 0, stream>>>(rel, out + OFF_RI);
}

// Round 17
// 984.590 us; speedup vs baseline: 1.0231x; 1.0231x over previous
//
#include <hip/hip_runtime.h>
#include <math.h>

typedef unsigned short u16;
typedef unsigned int u32;
typedef _Float16 f16;
typedef f16 f16x8 __attribute__((ext_vector_type(8)));
typedef float f32x4 __attribute__((ext_vector_type(4)));

#define DIM 512
#define D_IN 4096
#define N_OBJS 2048
#define N_RELS 32768
#define N_OBJ_CLS 151
#define N_REL_CLS 51
#define EPSV 1e-5f

// d_out layout (floats)
#define OFF_HOBJ  0
#define OFF_HEDGE (N_OBJS*DIM)
#define OFF_OLOG  (OFF_HEDGE + N_RELS*DIM)
#define OFF_PLOG  (OFF_OLOG + N_OBJS*N_OBJ_CLS)
#define OFF_LBL   (OFF_PLOG + N_RELS*N_REL_CLS)
#define OFF_RI    (OFF_LBL + N_OBJS)

__device__ __forceinline__ float sigmoidf_(float x) { return 1.0f / (1.0f + expf(-x)); }
__device__ __forceinline__ u16 f2h_(float f) {
    union { f16 h; u16 u; } c; c.h = (f16)f; return c.u;
}
__device__ __forceinline__ float h2f_(u16 u) {
    union { f16 h; u16 u; } c; c.u = u; return (float)c.h;
}

// 8 fp32 -> packed f16 (uint4)
__device__ __forceinline__ void cvt8h1(const float* f, uint4& h) {
    u32 hh[8];
#pragma unroll
    for (int i = 0; i < 8; i++) hh[i] = f2h_(f[i]);
    h.x = hh[0] | (hh[1] << 16); h.y = hh[2] | (hh[3] << 16);
    h.z = hh[4] | (hh[5] << 16); h.w = hh[6] | (hh[7] << 16);
}
// 8 fp32 -> hi + lo (a ~= hi + lo)
__device__ __forceinline__ void cvt8h2(const float* f, uint4& h, uint4& l) {
    u32 hh[8], ll[8];
#pragma unroll
    for (int i = 0; i < 8; i++) {
        u16 x = f2h_(f[i]);
        hh[i] = x;
        ll[i] = f2h_(f[i] - h2f_(x));
    }
    h.x = hh[0] | (hh[1] << 16); h.y = hh[2] | (hh[3] << 16);
    h.z = hh[4] | (hh[5] << 16); h.w = hh[6] | (hh[7] << 16);
    l.x = ll[0] | (ll[1] << 16); l.y = ll[2] | (ll[3] << 16);
    l.z = ll[4] | (ll[5] << 16); l.w = ll[6] | (ll[7] << 16);
}

// LDS offset (u16 units) for (row, chunk8) in a [rows][32] tile, XOR-swizzled
__device__ __forceinline__ int swzo(int row, int c) {
    return row * 32 + ((c ^ ((row >> 1) & 3)) << 3);
}

// XCD-chunked bijective blockIdx swizzle (requires nwg % 8 == 0)
__device__ __forceinline__ int xcdswz(int orig, int nwg) {
    const int q = nwg >> 3;
    return (orig & 7) * q + (orig >> 3);
}

// async global->LDS, 16B per lane; LDS dest = wave-uniform base + lane*16
__device__ __forceinline__ void gload16(const void* g, void* l) {
    __builtin_amdgcn_global_load_lds(
        (const __attribute__((address_space(1))) void*)g,
        (__attribute__((address_space(3))) void*)l, 16, 0, 0);
}

// ---------------------------------------------------------------------------
// ONE-SHOT weight conversion: all 10 fp32 weight tensors -> f16 in a single
// launch. Segment boundaries are compile-time constants (quad = ushort4 units).
// ---------------------------------------------------------------------------
#define Q_BIG  (DIM * D_IN / 4)          // 524288
#define Q_SQ   (DIM * DIM / 4)           // 65536
#define Q_GRU  (3 * DIM * DIM / 4)       // 196608
#define Q_OP   (N_OBJ_CLS * DIM / 4)     // 19328
#define Q_PP   (N_REL_CLS * DIM / 4)     // 6528
#define CV_C0  (Q_BIG)
#define CV_C1  (CV_C0 + Q_BIG)
#define CV_C2  (CV_C1 + Q_SQ)
#define CV_C3  (CV_C2 + Q_SQ)
#define CV_C4  (CV_C3 + Q_GRU)
#define CV_C5  (CV_C4 + Q_GRU)
#define CV_C6  (CV_C5 + Q_GRU)
#define CV_C7  (CV_C6 + Q_GRU)
#define CV_C8  (CV_C7 + Q_OP)
#define CV_C9  (CV_C8 + Q_PP)            // total quads = 1991936

__global__ __launch_bounds__(256) void convert_all(
    const float* __restrict__ s0, u16* __restrict__ d0,
    const float* __restrict__ s1, u16* __restrict__ d1,
    const float* __restrict__ s2, u16* __restrict__ d2,
    const float* __restrict__ s3, u16* __restrict__ d3,
    const float* __restrict__ s4, u16* __restrict__ d4,
    const float* __restrict__ s5, u16* __restrict__ d5,
    const float* __restrict__ s6, u16* __restrict__ d6,
    const float* __restrict__ s7, u16* __restrict__ d7,
    const float* __restrict__ s8, u16* __restrict__ d8,
    const float* __restrict__ s9, u16* __restrict__ d9)
{
    int i = blockIdx.x * 256 + threadIdx.x;
    if (i >= CV_C9) return;
    const float* src; u16* dst; int base;
    if      (i < CV_C0) { src = s0; dst = d0; base = 0; }
    else if (i < CV_C1) { src = s1; dst = d1; base = CV_C0; }
    else if (i < CV_C2) { src = s2; dst = d2; base = CV_C1; }
    else if (i < CV_C3) { src = s3; dst = d3; base = CV_C2; }
    else if (i < CV_C4) { src = s4; dst = d4; base = CV_C3; }
    else if (i < CV_C5) { src = s5; dst = d5; base = CV_C4; }
    else if (i < CV_C6) { src = s6; dst = d6; base = CV_C5; }
    else if (i < CV_C7) { src = s7; dst = d7; base = CV_C6; }
    else if (i < CV_C8) { src = s8; dst = d8; base = CV_C7; }
    else                { src = s9; dst = d9; base = CV_C8; }
    const int q = i - base;
    const float4 v = ((const float4*)src)[q];
    ((ushort4*)dst)[q] = make_ushort4(f2h_(v.x), f2h_(v.y), f2h_(v.z), f2h_(v.w));
}

// ---------------------------------------------------------------------------
// BODY: f16 GEMM, fp32 A split on the fly (AT terms), 1-deep A-reg prefetch,
// B f16 via global_load_lds. Caller provides LDS. BK=32, N = NX*128 exact.
// ---------------------------------------------------------------------------
template<bool RELU, int AT, bool WSPLIT>
__device__ __forceinline__ void gemm_a32_body(
    int id, u16* sAh, u16* sBh, u16* sAl,
    const float* __restrict__ A, const u16* __restrict__ Bhi,
    const float* __restrict__ bias, u16* __restrict__ Chi, u16* __restrict__ Clo,
    int NX, int K)
{
    const int m0 = (id / NX) * 128, n0 = (id % NX) * 128;
    const int N = NX * 128;
    const int t = threadIdx.x;
    const int wid = t >> 6, lane = t & 63;
    const int wm = (wid >> 1) * 64, wn = (wid & 1) * 64;
    const int lr = lane & 15, lk = lane >> 4;

    f32x4 acc[4][4] = {};

    const int sr = t >> 1;
    const int sc = (t & 1) * 2;
    const float* Ap = A + (size_t)(m0 + sr) * K + (t & 1) * 16;

    const int rB = (wid * 2) * 16 + (lane >> 2);
    const int cB = (lane & 3) ^ ((rB >> 1) & 3);
    const u16* Bp0 = Bhi + (size_t)(n0 + rB) * K + cB * 8;
    const u16* Bp1 = Bp0 + (size_t)16 * K;
    u16* Bd0 = &sBh[(wid * 2) * 512];
    u16* Bd1 = Bd0 + 512;

    float fv[16];
    *(float4*)&fv[0]  = *(const float4*)(Ap);
    *(float4*)&fv[4]  = *(const float4*)(Ap + 4);
    *(float4*)&fv[8]  = *(const float4*)(Ap + 8);
    *(float4*)&fv[12] = *(const float4*)(Ap + 12);

    for (int k0 = 0; k0 < K; k0 += 32) {
        uint4 ah0, ah1, al0, al1;
        if (AT == 2) { cvt8h2(fv, ah0, al0); cvt8h2(fv + 8, ah1, al1); }
        else         { cvt8h1(fv, ah0);      cvt8h1(fv + 8, ah1); }

        __syncthreads();                       // previous LDS reads complete
        gload16(Bp0 + k0, Bd0);
        gload16(Bp1 + k0, Bd1);
        *(uint4*)&sAh[swzo(sr, sc)]     = ah0;
        *(uint4*)&sAh[swzo(sr, sc + 1)] = ah1;
        if (AT == 2) {
            *(uint4*)&sAl[swzo(sr, sc)]     = al0;
            *(uint4*)&sAl[swzo(sr, sc + 1)] = al1;
        }
        asm volatile("s_waitcnt vmcnt(0)" ::: "memory");
        __syncthreads();

        const int kn = k0 + 32;
        if (kn < K) {
            *(float4*)&fv[0]  = *(const float4*)(Ap + kn);
            *(float4*)&fv[4]  = *(const float4*)(Ap + kn + 4);
            *(float4*)&fv[8]  = *(const float4*)(Ap + kn + 8);
            *(float4*)&fv[12] = *(const float4*)(Ap + kn + 12);
        }

        f16x8 ah[4], al[4], bh[4];
#pragma unroll
        for (int f = 0; f < 4; f++) {
            const int off = swzo(wm + f * 16 + lr, lk);
            ah[f] = *(const f16x8*)&sAh[off];
            if (AT == 2) al[f] = *(const f16x8*)&sAl[off];
            bh[f] = *(const f16x8*)&sBh[swzo(wn + f * 16 + lr, lk)];
        }
#pragma unroll
        for (int fm = 0; fm < 4; fm++)
#pragma unroll
            for (int fn = 0; fn < 4; fn++) {
                acc[fm][fn] = __builtin_amdgcn_mfma_f32_16x16x32_f16(ah[fm], bh[fn], acc[fm][fn], 0, 0, 0);
                if (AT == 2)
                    acc[fm][fn] = __builtin_amdgcn_mfma_f32_16x16x32_f16(al[fm], bh[fn], acc[fm][fn], 0, 0, 0);
            }
    }
#pragma unroll
    for (int fm = 0; fm < 4; fm++) {
        const int mrow = m0 + wm + fm * 16 + lk * 4;
#pragma unroll
        for (int fn = 0; fn < 4; fn++) {
            const int col = n0 + wn + fn * 16 + lr;
            const float bv = bias[col];
#pragma unroll
            for (int j = 0; j < 4; j++) {
                float v = acc[fm][fn][j] + bv;
                if (RELU) v = fmaxf(v, 0.0f);
                const u16 h = f2h_(v);
                Chi[(size_t)(mrow + j) * N + col] = h;
                if (WSPLIT) Clo[(size_t)(mrow + j) * N + col] = f2h_(v - h2f_(h));
            }
        }
    }
}

// FUSED enc1: ids [0,1024) = edge (AT1), ids [1024,1088) = obj (AT2, split out)
__global__ __launch_bounds__(256, 3) void enc1_both(
    const float* __restrict__ xp, const u16* __restrict__ pw,
    const float* __restrict__ pb, u16* __restrict__ tmpe,
    const float* __restrict__ xo, const u16* __restrict__ ow,
    const float* __restrict__ ob, u16* __restrict__ tmpoh, u16* __restrict__ tmpol)
{
    __shared__ u16 smem[3 * 4096];
    const int id = xcdswz(blockIdx.x, gridDim.x);
    if (id < 1024)
        gemm_a32_body<true, 1, false>(id, smem, smem + 4096, nullptr,
                                      xp, pw, pb, tmpe, nullptr, 4, D_IN);
    else
        gemm_a32_body<true, 2, true>(id - 1024, smem, smem + 4096, smem + 8192,
                                     xo, ow, ob, tmpoh, tmpol, 4, D_IN);
}

// ---------------------------------------------------------------------------
// BODY: f16 GEMM, A presplit (hi [+lo if AT=2]), B f16; all via gload_lds.
// BK=64. LDS: sA0=0, sA1=4096, sB0=8192, sB1=12288, [sL0=16384, sL1=20480].
// ---------------------------------------------------------------------------
template<int AT, bool WF32, bool WHI, bool WLO>
__device__ __forceinline__ void gemm_f16_body(
    int id, u16* smem,
    const u16* __restrict__ Ahi, const u16* __restrict__ Alo,
    const u16* __restrict__ Bhi, const float* __restrict__ bias,
    float* __restrict__ C32, u16* __restrict__ Chi, u16* __restrict__ Clo,
    int NX, int N, int ldc, int K)
{
    const int m0 = (id / NX) * 128, n0 = (id % NX) * 128;
    const int t = threadIdx.x;
    const int wid = t >> 6, lane = t & 63;
    const int wm = (wid >> 1) * 64, wn = (wid & 1) * 64;
    const int lr = lane & 15, lk = lane >> 4;

    f32x4 acc[4][4] = {};

    const int rr = (wid * 2) * 16 + (lane >> 2);
    const int cc = (lane & 3) ^ ((rr >> 1) & 3);
    const u16* pA0 = Ahi + (size_t)(m0 + rr) * K + cc * 8;
    const u16* pA1 = pA0 + (size_t)16 * K;
    const u16* pL0 = (AT == 2) ? Alo + (size_t)(m0 + rr) * K + cc * 8 : nullptr;
    const u16* pL1 = (AT == 2) ? pL0 + (size_t)16 * K : nullptr;
    const u16* pB0 = Bhi + (size_t)(n0 + rr) * K + cc * 8;
    const u16* pB1 = pB0 + (size_t)16 * K;
    const int bOff = (wid * 2) * 512;

    for (int k0 = 0; k0 < K; k0 += 64) {
        __syncthreads();
#pragma unroll
        for (int h = 0; h < 2; h++) {
            const int kk = k0 + h * 32;
            u16* sA_ = smem + h * 4096;
            u16* sB_ = smem + 8192 + h * 4096;
            gload16(pA0 + kk, sA_ + bOff);
            gload16(pA1 + kk, sA_ + bOff + 512);
            if (AT == 2) {
                u16* sL_ = smem + 16384 + h * 4096;
                gload16(pL0 + kk, sL_ + bOff);
                gload16(pL1 + kk, sL_ + bOff + 512);
            }
            gload16(pB0 + kk, sB_ + bOff);
            gload16(pB1 + kk, sB_ + bOff + 512);
        }
        asm volatile("s_waitcnt vmcnt(0)" ::: "memory");
        __syncthreads();

#pragma unroll
        for (int h = 0; h < 2; h++) {
            const u16* sA_ = smem + h * 4096;
            const u16* sB_ = smem + 8192 + h * 4096;
            const u16* sL_ = smem + 16384 + h * 4096;
            f16x8 ah[4], al[4], bh[4];
#pragma unroll
            for (int f = 0; f < 4; f++) {
                const int off = swzo(wm + f * 16 + lr, lk);
                ah[f] = *(const f16x8*)&sA_[off];
                if (AT == 2) al[f] = *(const f16x8*)&sL_[off];
                bh[f] = *(const f16x8*)&sB_[swzo(wn + f * 16 + lr, lk)];
            }
#pragma unroll
            for (int fm = 0; fm < 4; fm++)
#pragma unroll
                for (int fn = 0; fn < 4; fn++) {
                    acc[fm][fn] = __builtin_amdgcn_mfma_f32_16x16x32_f16(ah[fm], bh[fn], acc[fm][fn], 0, 0, 0);
                    if (AT == 2)
                        acc[fm][fn] = __builtin_amdgcn_mfma_f32_16x16x32_f16(al[fm], bh[fn], acc[fm][fn], 0, 0, 0);
                }
        }
    }
#pragma unroll
    for (int fm = 0; fm < 4; fm++) {
        const int mrow = m0 + wm + fm * 16 + lk * 4;
#pragma unroll
        for (int fn = 0; fn < 4; fn++) {
            const int col = n0 + wn + fn * 16 + lr;
            const float bv = bias[col];
#pragma unroll
            for (int j = 0; j < 4; j++) {
                const float v = acc[fm][fn][j] + bv;
                if (WF32 && col < N) C32[(size_t)(mrow + j) * ldc + col] = v;
                if (WHI) {
                    const u16 h = f2h_(v);
                    Chi[(size_t)(mrow + j) * (NX * 128) + col] = h;
                    if (WLO)
                        Clo[(size_t)(mrow + j) * (NX * 128) + col] = f2h_(v - h2f_(h));
                }
            }
        }
    }
}

// Standalone presplit GEMM kernels (enc2)
template<int AT, bool WF32, bool WHI, bool WLO>
__global__ __launch_bounds__(256, AT == 1 ? 4 : 3) void gemm_f16(
    const u16* __restrict__ Ahi, const u16* __restrict__ Alo,
    const u16* __restrict__ Bhi, const float* __restrict__ bias,
    float* __restrict__ C32, u16* __restrict__ Chi, u16* __restrict__ Clo,
    int NX, int N, int ldc, int K)
{
    __shared__ u16 smem[AT == 2 ? 6 * 4096 : 4 * 4096];
    const int id = xcdswz(blockIdx.x, gridDim.x);
    gemm_f16_body<AT, WF32, WHI, WLO>(id, smem, Ahi, Alo, Bhi, bias,
                                      C32, Chi, Clo, NX, N, ldc, K);
}

// FUSED classifiers: ids [0,256) = edge cls (AT1), [256,288) = obj cls (AT2)
__global__ __launch_bounds__(256, 3) void cls_both(
    const u16* __restrict__ hhe, const u16* __restrict__ pph,
    const float* __restrict__ ppb, float* __restrict__ plog,
    const u16* __restrict__ hhoh, const u16* __restrict__ hhol,
    const u16* __restrict__ oph, const float* __restrict__ opb,
    float* __restrict__ olog)
{
    __shared__ u16 smem[6 * 4096];
    const int id = xcdswz(blockIdx.x, gridDim.x);
    if (id < 256)
        gemm_f16_body<1, true, false, false>(id, smem, hhe, nullptr, pph, ppb,
                                             plog, nullptr, nullptr,
                                             1, N_REL_CLS, N_REL_CLS, DIM);
    else
        gemm_f16_body<2, true, false, false>(id - 256, smem, hhoh, hhol, oph, opb,
                                             olog, nullptr, nullptr,
                                             2, N_OBJ_CLS, N_OBJ_CLS, DIM);
}

// ---------------------------------------------------------------------------
// Merged GRU GEMM: part<12 -> gi = X@Wih^T+bih; part>=12 -> gh = H@Whh^T+bhh.
// A presplit (AT terms), BK=64, f16 out ldc=1536. 1D grid, XCD-swizzled.
// ---------------------------------------------------------------------------
template<int AT>
__global__ __launch_bounds__(256, AT == 1 ? 4 : 3) void gru_gemm2(
    const u16* __restrict__ Xh, const u16* __restrict__ Xl,
    const u16* __restrict__ WiH, const float* __restrict__ bi, u16* __restrict__ gi,
    const u16* __restrict__ Hh, const u16* __restrict__ Hl,
    const u16* __restrict__ WhH, const float* __restrict__ bhs, u16* __restrict__ gh_,
    int K)
{
    __shared__ u16 smem[AT == 2 ? 6 * 4096 : 4 * 4096];
    const int id = xcdswz(blockIdx.x, gridDim.x);
    const int part = id % 24;
    const int m0b = id / 24;
    const bool isH = part >= 12;
    const u16* Ahi = isH ? Hh : Xh;
    const u16* Alo = isH ? Hl : Xl;
    const u16* Bhi = isH ? WhH : WiH;
    const float* bias = isH ? bhs : bi;
    u16* C = isH ? gh_ : gi;
    const int nblk = part - (isH ? 12 : 0);
    gemm_f16_body<AT, false, true, false>(m0b * 12 + nblk, smem,
                                          Ahi, Alo, Bhi, bias,
                                          nullptr, C, nullptr, 12, 1536, 1536, K);
}

// ---------------------------------------------------------------------------
// GRU combine: gi/gh f16 [R x 1536]; old h read from f16 shadow (hi [+lo]);
// writes shadow (hi [+lo]) and optionally the final f32 state.
// ---------------------------------------------------------------------------
__device__ __forceinline__ float gcomb(u16 ir, u16 iz, u16 in_, u16 hr, u16 hz,
                                       u16 hn, float h) {
    const float r = sigmoidf_(h2f_(ir) + h2f_(hr));
    const float z = sigmoidf_(h2f_(iz) + h2f_(hz));
    const float n = tanhf(h2f_(in_) + r * h2f_(hn));
    return (1.0f - z) * n + z * h;
}

template<bool WSPLIT, bool WF32>
__global__ __launch_bounds__(256) void gru_combine(
    const u16* __restrict__ gi, const u16* __restrict__ gh,
    u16* __restrict__ hh, u16* __restrict__ hl, float* __restrict__ H32, int R)
{
    const int idx = blockIdx.x * 256 + threadIdx.x;      // R*128 quads
    if (idx >= R * 128) return;
    const int r = idx >> 7, c4 = (idx & 127) * 4;
    const size_t gb = (size_t)r * 1536 + c4;
    const ushort4 ir4 = *(const ushort4*)&gi[gb];
    const ushort4 iz4 = *(const ushort4*)&gi[gb + 512];
    const ushort4 in4 = *(const ushort4*)&gi[gb + 1024];
    const ushort4 hr4 = *(const ushort4*)&gh[gb];
    const ushort4 hz4 = *(const ushort4*)&gh[gb + 512];
    const ushort4 hn4 = *(const ushort4*)&gh[gb + 1024];
    const size_t hb = (size_t)r * 512 + c4;
    const ushort4 hhi = *(const ushort4*)&hh[hb];
    float h0 = h2f_(hhi.x), h1 = h2f_(hhi.y), h2 = h2f_(hhi.z), h3 = h2f_(hhi.w);
    if (WSPLIT) {
        const ushort4 hlo = *(const ushort4*)&hl[hb];
        h0 += h2f_(hlo.x); h1 += h2f_(hlo.y); h2 += h2f_(hlo.z); h3 += h2f_(hlo.w);
    }
    float4 o;
    o.x = gcomb(ir4.x, iz4.x, in4.x, hr4.x, hz4.x, hn4.x, h0);
    o.y = gcomb(ir4.y, iz4.y, in4.y, hr4.y, hz4.y, hn4.y, h1);
    o.z = gcomb(ir4.z, iz4.z, in4.z, hr4.z, hz4.z, hn4.z, h2);
    o.w = gcomb(ir4.w, iz4.w, in4.w, hr4.w, hz4.w, hn4.w, h3);
    const ushort4 hi4 = make_ushort4(f2h_(o.x), f2h_(o.y), f2h_(o.z), f2h_(o.w));
    *(ushort4*)&hh[hb] = hi4;
    if (WSPLIT) {
        *(ushort4*)&hl[hb] = make_ushort4(
            f2h_(o.x - h2f_(hi4.x)), f2h_(o.y - h2f_(hi4.y)),
            f2h_(o.z - h2f_(hi4.z)), f2h_(o.w - h2f_(hi4.w)));
    }
    if (WF32) *(float4*)&H32[hb] = o;
}

// ---------------------------------------------------------------------------
// CSR build
// ---------------------------------------------------------------------------
__global__ __launch_bounds__(256) void count_int(const int* __restrict__ rel,
                                                 int* cs, int* co)
{
    const int e = blockIdx.x * 256 + threadIdx.x;
    atomicAdd(&cs[rel[2 * e]], 1);
    atomicAdd(&co[rel[2 * e + 1]], 1);
}

__global__ __launch_bounds__(256) void scan_off(const int* __restrict__ cs,
    const int* __restrict__ co, int* __restrict__ offs, int* __restrict__ offo)
{
    __shared__ int tmp[256];
    for (int arr = 0; arr < 2; arr++) {
        const int* c = arr ? co : cs;
        int* off = arr ? offo : offs;
        const int base = threadIdx.x * 8;
        int loc[8]; int s = 0;
#pragma unroll
        for (int j = 0; j < 8; j++) { loc[j] = c[base + j]; s += loc[j]; }
        tmp[threadIdx.x] = s;
        __syncthreads();
        for (int d = 1; d < 256; d <<= 1) {
            const int v = (threadIdx.x >= d) ? tmp[threadIdx.x - d] : 0;
            __syncthreads();
            tmp[threadIdx.x] += v;
            __syncthreads();
        }
        int p = tmp[threadIdx.x] - s;    // exclusive prefix
#pragma unroll
        for (int j = 0; j < 8; j++) { off[base + j] = p; p += loc[j]; }
        __syncthreads();
    }
}

__global__ __launch_bounds__(256) void fill_csr(const int* __restrict__ rel,
    int* curS, int* curO, const int* __restrict__ offs, const int* __restrict__ offo,
    int* __restrict__ listS, int* __restrict__ listO)
{
    const int e = blockIdx.x * 256 + threadIdx.x;
    const int s = rel[2 * e], o = rel[2 * e + 1];
    const int i = atomicAdd(&curS[s], 1);
    listS[offs[s] + i] = e;
    const int j = atomicAdd(&curO[o], 1);
    listO[offo[o] + j] = e;
}

// ---------------------------------------------------------------------------
// Gates + edge messages, one WAVE per edge (no barrier, no atomics).
// ---------------------------------------------------------------------------
__global__ __launch_bounds__(256) void gatepass(
    const u16* __restrict__ hho, const u16* __restrict__ hhe,
    const int* __restrict__ rel,
    const float* __restrict__ wsn, const float* __restrict__ bsn,
    const float* __restrict__ won, const float* __restrict__ bon,
    const float* __restrict__ wse, const float* __restrict__ bse,
    const float* __restrict__ woe, const float* __restrict__ boe,
    const int* __restrict__ cs, const int* __restrict__ co,
    u16* __restrict__ emh, float* __restrict__ af, float* __restrict__ ag)
{
    const int e = blockIdx.x * 4 + (threadIdx.x >> 6);
    const int lane = threadIdx.x & 63;
    const int s = rel[2 * e], o = rel[2 * e + 1];
    const int c = lane * 8;

    const uint4 hsu = *(const uint4*)&hho[(size_t)s * DIM + c];
    const uint4 hou = *(const uint4*)&hho[(size_t)o * DIM + c];
    const uint4 heu = *(const uint4*)&hhe[(size_t)e * DIM + c];
    float hs[8], ho[8], he[8];
    hs[0] = h2f_((u16)hsu.x); hs[1] = h2f_((u16)(hsu.x >> 16));
    hs[2] = h2f_((u16)hsu.y); hs[3] = h2f_((u16)(hsu.y >> 16));
    hs[4] = h2f_((u16)hsu.z); hs[5] = h2f_((u16)(hsu.z >> 16));
    hs[6] = h2f_((u16)hsu.w); hs[7] = h2f_((u16)(hsu.w >> 16));
    ho[0] = h2f_((u16)hou.x); ho[1] = h2f_((u16)(hou.x >> 16));
    ho[2] = h2f_((u16)hou.y); ho[3] = h2f_((u16)(hou.y >> 16));
    ho[4] = h2f_((u16)hou.z); ho[5] = h2f_((u16)(hou.z >> 16));
    ho[6] = h2f_((u16)hou.w); ho[7] = h2f_((u16)(hou.w >> 16));
    he[0] = h2f_((u16)heu.x); he[1] = h2f_((u16)(heu.x >> 16));
    he[2] = h2f_((u16)heu.y); he[3] = h2f_((u16)(heu.y >> 16));
    he[4] = h2f_((u16)heu.z); he[5] = h2f_((u16)(heu.z >> 16));
    he[6] = h2f_((u16)heu.w); he[7] = h2f_((u16)(heu.w >> 16));

    float p0 = 0.f, p1 = 0.f, p2 = 0.f, p3 = 0.f;
#pragma unroll
    for (int q = 0; q < 2; q++) {
        const float4 w0v = *(const float4*)&wsn[c + q * 4];
        const float4 w0e = *(const float4*)&wsn[DIM + c + q * 4];
        const float4 w1v = *(const float4*)&won[c + q * 4];
        const float4 w1e = *(const float4*)&won[DIM + c + q * 4];
        const float4 w2v = *(const float4*)&wse[c + q * 4];
        const float4 w2e = *(const float4*)&wse[DIM + c + q * 4];
        const float4 w3v = *(const float4*)&woe[c + q * 4];
        const float4 w3e = *(const float4*)&woe[DIM + c + q * 4];
        const float* s4 = &hs[q * 4];
        const float* o4 = &ho[q * 4];
        const float* e4 = &he[q * 4];
        p0 += s4[0]*w0v.x + s4[1]*w0v.y + s4[2]*w0v.z + s4[3]*w0v.w
            + e4[0]*w0e.x + e4[1]*w0e.y + e4[2]*w0e.z + e4[3]*w0e.w;
        p1 += o4[0]*w1v.x + o4[1]*w1v.y + o4[2]*w1v.z + o4[3]*w1v.w
            + e4[0]*w1e.x + e4[1]*w1e.y + e4[2]*w1e.z + e4[3]*w1e.w;
        p2 += s4[0]*w2v.x + s4[1]*w2v.y + s4[2]*w2v.z + s4[3]*w2v.w
            + e4[0]*w2e.x + e4[1]*w2e.y + e4[2]*w2e.z + e4[3]*w2e.w;
        p3 += o4[0]*w3v.x + o4[1]*w3v.y + o4[2]*w3v.z + o4[3]*w3v.w
            + e4[0]*w3e.x + e4[1]*w3e.y + e4[2]*w3e.z + e4[3]*w3e.w;
    }
#pragma unroll
    for (int off = 32; off; off >>= 1) {
        p0 += __shfl_xor(p0, off);
        p1 += __shfl_xor(p1, off);
        p2 += __shfl_xor(p2, off);
        p3 += __shfl_xor(p3, off);
    }
    const float gsn = sigmoidf_(p0 + bsn[0]);
    const float gon = sigmoidf_(p1 + bon[0]);
    const float gse = sigmoidf_(p2 + bse[0]);
    const float goe = sigmoidf_(p3 + boe[0]);

    if (lane == 0) {
        af[e] = 0.5f * gsn / ((float)cs[s] + EPSV);
        ag[e] = 0.5f * gon / ((float)co[o] + EPSV);
    }
    u16 em8[8];
#pragma unroll
    for (int j = 0; j < 8; j++)
        em8[j] = f2h_(0.5f * (gse * hs[j] + goe * ho[j]));
    *(uint4*)&emh[(size_t)e * DIM + c] = *(const uint4*)em8;
}

// ---------------------------------------------------------------------------
// Node-message gather (no atomics), reading f16 h_edge shadow.
// ---------------------------------------------------------------------------
__global__ __launch_bounds__(256) void gather_nm(
    const u16* __restrict__ hhe,
    const int* __restrict__ listS, const int* __restrict__ listO,
    const int* __restrict__ offs, const int* __restrict__ offo,
    const int* __restrict__ cs, const int* __restrict__ co,
    const float* __restrict__ af, const float* __restrict__ ag,
    u16* __restrict__ nmh, u16* __restrict__ nml)
{
    const int v = blockIdx.x * 4 + (threadIdx.x >> 6);
    const int lane = threadIdx.x & 63;
    const int c = lane * 8;

    float acc[8] = {};
#pragma unroll
    for (int side = 0; side < 2; side++) {
        const int* list = side ? listO : listS;
        const int b = side ? offo[v] : offs[v];
        const int n = side ? co[v] : cs[v];
        const float* coef = side ? ag : af;
        for (int i = 0; i < n; i++) {
            const int e = list[b + i];
            const float a = coef[e];
            const uint4 x = *(const uint4*)&hhe[(size_t)e * DIM + c];
            acc[0] += a * h2f_((u16)x.x); acc[1] += a * h2f_((u16)(x.x >> 16));
            acc[2] += a * h2f_((u16)x.y); acc[3] += a * h2f_((u16)(x.y >> 16));
            acc[4] += a * h2f_((u16)x.z); acc[5] += a * h2f_((u16)(x.z >> 16));
            acc[6] += a * h2f_((u16)x.w); acc[7] += a * h2f_((u16)(x.w >> 16));
        }
    }
    u16 hi8[8], lo8[8];
#pragma unroll
    for (int j = 0; j < 8; j++) {
        hi8[j] = f2h_(acc[j]);
        lo8[j] = f2h_(acc[j] - h2f_(hi8[j]));
    }
    *(uint4*)&nmh[(size_t)v * DIM + c] = *(const uint4*)hi8;
    *(uint4*)&nml[(size_t)v * DIM + c] = *(const uint4*)lo8;
}

// ---------------------------------------------------------------------------
__global__ __launch_bounds__(256) void argmax_kernel(const float* __restrict__ logits,
                                                     float* __restrict__ out)
{
    const int row = blockIdx.x * 4 + (threadIdx.x >> 6);
    const int lane = threadIdx.x & 63;
    float bv = -1e30f; int bi = 1;
    for (int j = 1 + lane; j < N_OBJ_CLS; j += 64) {
        const float v = logits[(size_t)row * N_OBJ_CLS + j];
        if (v > bv) { bv = v; bi = j; }
    }
#pragma unroll
    for (int off = 32; off; off >>= 1) {
        const float ov = __shfl_xor(bv, off);
        const int oi = __shfl_xor(bi, off);
        if (ov > bv || (ov == bv && oi < bi)) { bv = ov; bi = oi; }
    }
    if (lane == 0) out[row] = (float)bi;
}

__global__ __launch_bounds__(256) void relinds_kernel(const int* __restrict__ rel,
                                                      float* __restrict__ out)
{
    const int i = blockIdx.x * 256 + threadIdx.x;
    out[i] = (float)rel[i];
}

// ---------------------------------------------------------------------------
extern "C" void kernel_launch(void* const* d_in, const int* in_sizes, int n_in,
                              void* d_out, int out_size, void* d_ws, size_t ws_size,
                              hipStream_t stream)
{
    const float* x_obj = (const float*)d_in[0];
    const float* x_pred = (const float*)d_in[1];
    const int* rel = (const int*)d_in[2];
    const float* oe_w1 = (const float*)d_in[3];
    const float* oe_b1 = (const float*)d_in[4];
    const float* oe_w2 = (const float*)d_in[5];
    const float* oe_b2 = (const float*)d_in[6];
    const float* pe_w1 = (const float*)d_in[7];
    const float* pe_b1 = (const float*)d_in[8];
    const float* pe_w2 = (const float*)d_in[9];
    const float* pe_b2 = (const float*)d_in[10];
    const float* g_sn_w = (const float*)d_in[11];
    const float* g_sn_b = (const float*)d_in[12];
    const float* g_on_w = (const float*)d_in[13];
    const float* g_on_b = (const float*)d_in[14];
    const float* g_se_w = (const float*)d_in[15];
    const float* g_se_b = (const float*)d_in[16];
    const float* g_oe_w = (const float*)d_in[17];
    const float* g_oe_b = (const float*)d_in[18];
    const float* ngru_wih = (const float*)d_in[19];
    const float* ngru_whh = (const float*)d_in[20];
    const float* ngru_bih = (const float*)d_in[21];
    const float* ngru_bhh = (const float*)d_in[22];
    const float* egru_wih = (const float*)d_in[23];
    const float* egru_whh = (const float*)d_in[24];
    const float* egru_bih = (const float*)d_in[25];
    const float* egru_bhh = (const float*)d_in[26];
    const float* op_w = (const float*)d_in[27];
    const float* op_b = (const float*)d_in[28];
    const float* pp_w = (const float*)d_in[29];
    const float* pp_b = (const float*)d_in[30];

    float* out = (float*)d_out;

    float* h_obj = out + OFF_HOBJ;       // f32 state written only at final step
    float* h_edge = out + OFF_HEDGE;

    // ---- workspace layout ----
    char* wsp = (char*)d_ws;
    float* af = (float*)wsp; wsp += N_RELS * 4;
    float* ag = (float*)wsp; wsp += N_RELS * 4;
    int* cs = (int*)wsp;   wsp += N_OBJS * 4;
    int* co = (int*)wsp;   wsp += N_OBJS * 4;
    int* offs = (int*)wsp; wsp += N_OBJS * 4;
    int* offo = (int*)wsp; wsp += N_OBJS * 4;
    int* curS = (int*)wsp; wsp += N_OBJS * 4;
    int* curO = (int*)wsp; wsp += N_OBJS * 4;
    int* listS = (int*)wsp; wsp += N_RELS * 4;
    int* listO = (int*)wsp; wsp += N_RELS * 4;

    u16* wp = (u16*)wsp;
    const int s_big = DIM * D_IN, s_sq = DIM * DIM, s_gru = 3 * DIM * DIM;
    // weights (f16)
    u16 *oe1h = wp; wp += s_big;
    u16 *pe1h = wp; wp += s_big;
    u16 *oe2h = wp; wp += s_sq;
    u16 *pe2h = wp; wp += s_sq;
    u16 *nih_h = wp; wp += s_gru;
    u16 *nhh_h = wp; wp += s_gru;
    u16 *eih_h = wp; wp += s_gru;
    u16 *ehh_h = wp; wp += s_gru;
    u16 *oph = wp; wp += 256 * DIM;
    u16 *pph = wp; wp += 128 * DIM;
    // f16 activations
    u16 *tmpo_h = wp; wp += (size_t)N_OBJS * DIM;   // enc1-obj out hi
    u16 *tmpo_l = wp; wp += (size_t)N_OBJS * DIM;   // enc1-obj out lo
    u16 *tmpe_h = wp; wp += (size_t)N_RELS * DIM;   // enc1-edge out (1-term)
    u16 *hhoh = wp; wp += (size_t)N_OBJS * DIM;     // h_obj shadow hi
    u16 *hhol = wp; wp += (size_t)N_OBJS * DIM;     // h_obj shadow lo
    u16 *hhe  = wp; wp += (size_t)N_RELS * DIM;     // h_edge shadow (1-term)
    u16 *emh  = wp; wp += (size_t)N_RELS * DIM;     // edge messages f16
    u16 *nmh  = wp; wp += (size_t)N_OBJS * DIM;     // node messages hi
    u16 *nml  = wp; wp += (size_t)N_OBJS * DIM;     // node messages lo

    // gi/gh chunk buffers (f16, R x 1536 each)
    const size_t used = (size_t)((char*)wp - (char*)d_ws);
    int R = 8192;
    if (used + (size_t)16384 * 6144 <= ws_size) R = 16384;
    u16* gi = wp;
    u16* gh = gi + (size_t)R * 1536;

    // all weight conversions in ONE launch
    convert_all<<<(CV_C9 + 255) / 256, 256, 0, stream>>>(
        oe_w1, oe1h, pe_w1, pe1h, oe_w2, oe2h, pe_w2, pe2h,
        ngru_wih, nih_h, ngru_whh, nhh_h, egru_wih, eih_h, egru_whh, ehh_h,
        op_w, oph, pp_w, pph);

    // CSR build
    hipMemsetAsync(cs, 0, 2 * N_OBJS * sizeof(int), stream);
    hipMemsetAsync(curS, 0, 2 * N_OBJS * sizeof(int), stream);
    count_int<<<N_RELS / 256, 256, 0, stream>>>(rel, cs, co);
    scan_off<<<1, 256, 0, stream>>>(cs, co, offs, offo);
    fill_csr<<<N_RELS / 256, 256, 0, stream>>>(rel, curS, curO, offs, offo, listS, listO);

    // enc1: FUSED edge(1-term) + obj(2-term split-out) in one launch
    enc1_both<<<1088, 256, 0, stream>>>(
        x_pred, pe1h, pe_b1, tmpe_h,
        x_obj, oe1h, oe_b1, tmpo_h, tmpo_l);
    // enc2: separate (preserves edge AT1 occupancy)
    gemm_f16<1, false, true, false><<<4 * (N_RELS / 128), 256, 0, stream>>>(
        tmpe_h, nullptr, pe2h, pe_b2, nullptr, hhe, nullptr, 4, DIM, DIM, DIM);
    gemm_f16<2, false, true, true><<<4 * (N_OBJS / 128), 256, 0, stream>>>(
        tmpo_h, tmpo_l, oe2h, oe_b2, nullptr, hhoh, hhol, 4, DIM, DIM, DIM);

    // message-passing steps (f16 state between steps; f32 out at last step)
    for (int step = 0; step < 2; step++) {
        gatepass<<<N_RELS / 4, 256, 0, stream>>>(
            hhoh, hhe, rel,
            g_sn_w, g_sn_b, g_on_w, g_on_b, g_se_w, g_se_b, g_oe_w, g_oe_b,
            cs, co, emh, af, ag);
        gather_nm<<<N_OBJS / 4, 256, 0, stream>>>(
            hhe, listS, listO, offs, offo, cs, co, af, ag, nmh, nml);

        // obj GRU (2-term)
        gru_gemm2<2><<<24 * (N_OBJS / 128), 256, 0, stream>>>(
            nmh, nml, nih_h, ngru_bih, gi, hhoh, hhol, nhh_h, ngru_bhh, gh, DIM);
        if (step == 0)
            gru_combine<true, false><<<(N_OBJS * 128 + 255) / 256, 256, 0, stream>>>(
                gi, gh, hhoh, hhol, nullptr, N_OBJS);
        else
            gru_combine<true, true><<<(N_OBJS * 128 + 255) / 256, 256, 0, stream>>>(
                gi, gh, hhoh, hhol, h_obj, N_OBJS);

        // edge GRU (1-term), chunked
        for (int r0 = 0; r0 < N_RELS; r0 += R) {
            const int Rc = (N_RELS - r0 < R) ? (N_RELS - r0) : R;
            gru_gemm2<1><<<24 * (Rc / 128), 256, 0, stream>>>(
                emh + (size_t)r0 * DIM, nullptr, eih_h, egru_bih, gi,
                hhe + (size_t)r0 * DIM, nullptr, ehh_h, egru_bhh, gh, DIM);
            if (step == 0)
                gru_combine<false, false><<<(Rc * 128 + 255) / 256, 256, 0, stream>>>(
                    gi, gh, hhe + (size_t)r0 * DIM, nullptr, nullptr, Rc);
            else
                gru_combine<false, true><<<(Rc * 128 + 255) / 256, 256, 0, stream>>>(
                    gi, gh, hhe + (size_t)r0 * DIM, nullptr, h_edge + (size_t)r0 * DIM, Rc);
        }
    }

    // classifiers: FUSED edge(1-term) + obj(2-term, labels) in one launch
    cls_both<<<288, 256, 0, stream>>>(
        hhe, pph, pp_b, out + OFF_PLOG,
        hhoh, hhol, oph, op_b, out + OFF_OLOG);

    // labels + rel_inds passthrough
    argmax_kernel<<<N_OBJS / 4, 256, 0, stream>>>(out + OFF_OLOG, out + OFF_LBL);
    relinds_kernel<<<(2 * N_RELS) / 256, 256, 0, stream>>>(rel, out + OFF_RI);
}